// Round 1
// baseline (416.366 us; speedup 1.0000x reference)
//
#include <hip/hip_runtime.h>
#include <stdint.h>

#define HASH_BITS 19
#define HASH_SIZE (1u << HASH_BITS)

// One thread per position.
// positions: [N,2] float32; table: [HASH_SIZE, 8] float32; out: [N, 8] float32.
__global__ __launch_bounds__(256) void hashgrid2d_kernel(
    const float2* __restrict__ pos,   // N float2
    const float4* __restrict__ table, // HASH_SIZE*2 float4
    float4* __restrict__ out,         // N*2 float4
    int n)
{
    int i = blockIdx.x * blockDim.x + threadIdx.x;
    if (i >= n) return;

    float2 p = pos[i];
    // ix,iy in [0,4095] -> all hash intermediates stay positive & fit in 64 bits,
    // so uint64 arithmetic == reference int64 semantics exactly.
    uint64_t ix = (uint64_t)(int64_t)floorf(p.x);
    uint64_t iy = (uint64_t)(int64_t)floorf(p.y);

    uint64_t h = ix;
    h ^= (h >> 16);
    h *= 2246822507ull;
    h ^= (h >> 13);
    h += iy * 3266489909ull;
    h ^= (h >> 16);
    uint32_t idx = (uint32_t)(h & (uint64_t)(HASH_SIZE - 1));

    float4 a = table[(size_t)idx * 2 + 0];
    float4 b = table[(size_t)idx * 2 + 1];
    out[(size_t)i * 2 + 0] = a;
    out[(size_t)i * 2 + 1] = b;
}

extern "C" void kernel_launch(void* const* d_in, const int* in_sizes, int n_in,
                              void* d_out, int out_size, void* d_ws, size_t ws_size,
                              hipStream_t stream) {
    const float2* pos   = (const float2*)d_in[0];   // positions [N,2]
    const float4* table = (const float4*)d_in[1];   // table [HASH_SIZE,8]
    float4* out         = (float4*)d_out;           // [N,8]

    int n = in_sizes[0] / 2;  // N positions
    int block = 256;
    int grid = (n + block - 1) / block;
    hashgrid2d_kernel<<<grid, block, 0, stream>>>(pos, table, out, n);
}

// Round 3
// 411.302 us; speedup vs baseline: 1.0123x; 1.0123x over previous
//
#include <hip/hip_runtime.h>
#include <stdint.h>

#define HASH_BITS 19
#define HASH_SIZE (1u << HASH_BITS)

// Native clang vector types — __builtin_nontemporal_* requires these
// (HIP_vector_type structs are rejected by the builtin).
typedef float vfloat2 __attribute__((ext_vector_type(2)));
typedef float vfloat4 __attribute__((ext_vector_type(4)));

// Two threads per position: lane pair (2k, 2k+1) each fetch one 16B half of
// the same 32B table entry. Per gather instruction a wave then covers 32
// entries with pair-coalesced transactions (vs 64 divergent lines before),
// halving the L1/L2 request count for the random gather.
// positions/out are pure streams -> nontemporal so they don't evict table
// lines from L2 (table = 16 MiB, L2 = 4 MiB/XCD; every line kept matters).
__global__ __launch_bounds__(256) void hashgrid2d_kernel(
    const vfloat2* __restrict__ pos,   // N float2
    const vfloat4* __restrict__ table, // HASH_SIZE*2 float4
    vfloat4* __restrict__ out,         // N*2 float4
    int n)
{
    int t = blockIdx.x * blockDim.x + threadIdx.x;  // 0 .. 2n-1
    int p = t >> 1;        // position index
    int h = t & 1;         // which 16B half of the entry
    if (p >= n) return;

    vfloat2 q = __builtin_nontemporal_load(&pos[p]);
    // ix,iy in [0,4095] -> all hash intermediates stay positive & fit in 64
    // bits, so uint64 arithmetic == reference int64 semantics exactly.
    uint64_t ix = (uint64_t)(int64_t)floorf(q.x);
    uint64_t iy = (uint64_t)(int64_t)floorf(q.y);

    uint64_t hh = ix;
    hh ^= (hh >> 16);
    hh *= 2246822507ull;
    hh ^= (hh >> 13);
    hh += iy * 3266489909ull;
    hh ^= (hh >> 16);
    uint32_t idx = (uint32_t)(hh & (uint64_t)(HASH_SIZE - 1));

    vfloat4 v = table[(size_t)idx * 2 + h];   // keep in L2 (regular load)
    __builtin_nontemporal_store(v, &out[(size_t)p * 2 + h]);
}

extern "C" void kernel_launch(void* const* d_in, const int* in_sizes, int n_in,
                              void* d_out, int out_size, void* d_ws, size_t ws_size,
                              hipStream_t stream) {
    const vfloat2* pos   = (const vfloat2*)d_in[0];   // positions [N,2]
    const vfloat4* table = (const vfloat4*)d_in[1];   // table [HASH_SIZE,8]
    vfloat4* out         = (vfloat4*)d_out;           // [N,8]

    int n = in_sizes[0] / 2;  // N positions
    long long threads = 2LL * n;
    int block = 256;
    int grid = (int)((threads + block - 1) / block);
    hashgrid2d_kernel<<<grid, block, 0, stream>>>(pos, table, out, n);
}